// Round 1
// baseline (3814.373 us; speedup 1.0000x reference)
//
#include <hip/hip_runtime.h>
#include <hip/hip_bf16.h>

typedef unsigned short ushort_t;
typedef __attribute__((ext_vector_type(8))) short short8;
typedef __attribute__((ext_vector_type(4))) float f32x4;

__device__ __forceinline__ ushort_t f2bf(float f) {
    unsigned x = __builtin_bit_cast(unsigned, f);
    unsigned r = x + 0x7fffu + ((x >> 16) & 1u);
    return (ushort_t)(r >> 16);
}
__device__ __forceinline__ float bf2f(ushort_t u) {
    return __builtin_bit_cast(float, ((unsigned)u) << 16);
}

// ---------------- generic fp32 -> bf16 convert (optional relu) ----------------
template<bool RELU>
__global__ void k_conv(const float* __restrict__ src, ushort_t* __restrict__ dst, int n) {
    int i = (blockIdx.x * blockDim.x + threadIdx.x) * 4;
    int stride = gridDim.x * blockDim.x * 4;
    for (; i < n; i += stride) {
        float4 v = *(const float4*)(src + i);
        if (RELU) {
            v.x = fmaxf(v.x, 0.f); v.y = fmaxf(v.y, 0.f);
            v.z = fmaxf(v.z, 0.f); v.w = fmaxf(v.w, 0.f);
        }
        dst[i + 0] = f2bf(v.x); dst[i + 1] = f2bf(v.y);
        dst[i + 2] = f2bf(v.z); dst[i + 3] = f2bf(v.w);
    }
}

// ---------------- Whh -> fragment-ordered bf16 [16cg][6f][16kk][64lane][8e] ----
__global__ void k_whh_frag(const float* __restrict__ whh, ushort_t* __restrict__ out) {
    int idx = blockIdx.x * blockDim.x + threadIdx.x;
    if (idx >= 16 * 6 * 16 * 64 * 8) return;
    int e  = idx & 7;
    int s  = idx >> 3;
    int l  = s & 63;
    int s2 = s >> 6;
    int kk = s2 & 15;
    int s3 = s2 >> 4;
    int f  = s3 % 6;
    int j  = s3 / 6;
    int ng = (f >> 1) * 512 + j * 32 + (f & 1) * 16 + (l & 15);
    int k  = kk * 32 + ((l >> 4) << 3) + e;
    out[idx] = f2bf(whh[(size_t)ng * 512 + k]);
}

// ---------------- build feats bf16 [512][512] = [vec | e0 | e1 | e2] ----------
__global__ void k_feats(const float* __restrict__ vec, const int* __restrict__ wf,
                        const float* __restrict__ w0, const float* __restrict__ w1,
                        const float* __restrict__ w2, ushort_t* __restrict__ out) {
    int idx = blockIdx.x * blockDim.x + threadIdx.x;
    if (idx >= 512 * 512) return;
    int b = idx >> 9, k = idx & 511;
    float v;
    if (k < 128)       v = vec[b * 128 + k];
    else if (k < 256)  v = w0[wf[b * 3 + 0] * 128 + (k - 128)];
    else if (k < 384)  v = w1[wf[b * 3 + 1] * 128 + (k - 256)];
    else               v = w2[wf[b * 3 + 2] * 128 + (k - 384)];
    out[idx] = f2bf(v);
}

// ---------------- TN MFMA GEMM: C[M,N] = A[M,K](bf16) @ W[N,K]^T + bias -------
// 128x128 tile, BK=64, 4 waves. global_load_lds w/ pre-swizzled source (XOR row&7<<4).
template<bool RELU, bool OUTBF>
__global__ __launch_bounds__(256) void k_gemm(const ushort_t* __restrict__ A,
                                              const ushort_t* __restrict__ W,
                                              const float* __restrict__ bias,
                                              void* __restrict__ Cout,
                                              int M, int N, int K) {
    __shared__ __attribute__((aligned(16))) ushort_t As[128 * 64];
    __shared__ __attribute__((aligned(16))) ushort_t Ws[128 * 64];
    const int tid = threadIdx.x;
    const int lane = tid & 63, w = tid >> 6;
    const int wm = w >> 1, wn = w & 1;
    const int m0 = blockIdx.y * 128, n0 = blockIdx.x * 128;
    const int l16 = lane & 15, lq = lane >> 4;
    f32x4 acc[4][4] = {};

    for (int k0 = 0; k0 < K; k0 += 64) {
        // stage A (16KB) + W (16KB); 16 chunks of 1KB each, lane-linear LDS dest,
        // global source pre-swizzled so that LDS reads below can XOR-deswizzle.
        #pragma unroll
        for (int c = 0; c < 4; ++c) {
            int chunk = w * 4 + c;
            int d = chunk * 1024 + lane * 16;
            int row = d >> 7;
            int dlin = d ^ ((row & 7) << 4);
            int col = (dlin & 127) >> 1;
            const ushort_t* ga = A + (size_t)(m0 + row) * K + k0 + col;
            __builtin_amdgcn_global_load_lds(
                (const __attribute__((address_space(1))) void*)ga,
                (__attribute__((address_space(3))) void*)(((char*)As) + chunk * 1024),
                16, 0, 0);
        }
        #pragma unroll
        for (int c = 0; c < 4; ++c) {
            int chunk = w * 4 + c;
            int d = chunk * 1024 + lane * 16;
            int row = d >> 7;
            int dlin = d ^ ((row & 7) << 4);
            int col = (dlin & 127) >> 1;
            const ushort_t* gw = W + (size_t)(n0 + row) * K + k0 + col;
            __builtin_amdgcn_global_load_lds(
                (const __attribute__((address_space(1))) void*)gw,
                (__attribute__((address_space(3))) void*)(((char*)Ws) + chunk * 1024),
                16, 0, 0);
        }
        asm volatile("s_waitcnt vmcnt(0)" ::: "memory");
        __syncthreads();

        #pragma unroll
        for (int kk = 0; kk < 2; ++kk) {
            short8 af[4], bfr[4];
            #pragma unroll
            for (int m = 0; m < 4; ++m) {
                int row = wm * 64 + m * 16 + l16;
                int addr = (row * 128 + kk * 64 + lq * 16) ^ ((row & 7) << 4);
                af[m] = *(const short8*)((const char*)As + addr);
            }
            #pragma unroll
            for (int n = 0; n < 4; ++n) {
                int row = wn * 64 + n * 16 + l16;
                int addr = (row * 128 + kk * 64 + lq * 16) ^ ((row & 7) << 4);
                bfr[n] = *(const short8*)((const char*)Ws + addr);
            }
            #pragma unroll
            for (int m = 0; m < 4; ++m)
                #pragma unroll
                for (int n = 0; n < 4; ++n)
                    acc[m][n] = __builtin_amdgcn_mfma_f32_16x16x32_bf16(af[m], bfr[n], acc[m][n], 0, 0, 0);
        }
        __syncthreads();
    }

    #pragma unroll
    for (int m = 0; m < 4; ++m) {
        int row = m0 + wm * 64 + m * 16 + lq * 4;
        #pragma unroll
        for (int n = 0; n < 4; ++n) {
            int col = n0 + wn * 64 + n * 16 + l16;
            float bv = bias[col];
            #pragma unroll
            for (int r = 0; r < 4; ++r) {
                float v = acc[m][n][r] + bv;
                if (RELU) v = fmaxf(v, 0.f);
                if (OUTBF) ((ushort_t*)Cout)[(size_t)(row + r) * N + col] = f2bf(v);
                else       ((float*)Cout)[(size_t)(row + r) * N + col] = v;
            }
        }
    }
}

// ---------------- GRU recurrence: persistent cooperative, 256 blocks ---------
// block b: row-group rg = b&15 (32 batch rows), col-group cg = b>>4 (32 hid cols).
// Whh slice (96 gh-cols x 512) fragment-ordered in LDS. Hidden state exchanged
// via double-buffered global bf16 Hx with per-row-group flag barrier.
__global__ __launch_bounds__(128) void k_recur(const ushort_t* __restrict__ G,
                                               const ushort_t* __restrict__ WhhF,
                                               const int* __restrict__ goals,
                                               const float* __restrict__ bhh,
                                               ushort_t* __restrict__ Hx,
                                               int* __restrict__ flags,
                                               float* __restrict__ goal_out) {
    __shared__ __attribute__((aligned(16))) ushort_t Bs[6 * 16 * 64 * 8]; // 98304 B
    const int bid = blockIdx.x;
    const int rg = bid & 15;
    const int cg = bid >> 4;
    const int r0 = rg * 32, c0 = cg * 32;
    const int tid = threadIdx.x, lane = tid & 63, w = tid >> 6;
    const int l16 = lane & 15, lq = lane >> 4;

    // load Whh fragment slice: 98304B = 96 chunks of 1KB
    {
        const ushort_t* src = WhhF + (size_t)cg * 49152;
        for (int c = 0; c < 48; ++c) {
            int chunk = w * 48 + c;
            const ushort_t* ga = src + chunk * 512 + lane * 8;
            __builtin_amdgcn_global_load_lds(
                (const __attribute__((address_space(1))) void*)ga,
                (__attribute__((address_space(3))) void*)(((char*)Bs) + chunk * 1024),
                16, 0, 0);
        }
        asm volatile("s_waitcnt vmcnt(0)" ::: "memory");
        __syncthreads();
    }

    const int rowbase = r0 + w * 16;
    float hst[2][4];
    #pragma unroll
    for (int q = 0; q < 2; ++q)
        #pragma unroll
        for (int r = 0; r < 4; ++r) hst[q][r] = 0.f;

    float bh[3][2];
    #pragma unroll
    for (int g = 0; g < 3; ++g)
        #pragma unroll
        for (int q = 0; q < 2; ++q) bh[g][q] = bhh[g * 512 + c0 + q * 16 + l16];

    for (int t = 0; t < 128; ++t) {
        const ushort_t* hb = Hx + ((size_t)(t & 1) << 18);
        short8 af[16];
        #pragma unroll
        for (int kk = 0; kk < 16; ++kk) {
            const ushort_t* pa = hb + (size_t)(rowbase + l16) * 512 + kk * 32 + lq * 8;
            af[kk] = *(const short8*)pa;
        }
        f32x4 acc[6] = {};
        #pragma unroll
        for (int kk = 0; kk < 16; ++kk) {
            #pragma unroll
            for (int f = 0; f < 6; ++f) {
                short8 bfr = *(const short8*)((const char*)Bs + ((f * 16 + kk) * 64 + lane) * 16);
                acc[f] = __builtin_amdgcn_mfma_f32_16x16x32_bf16(af[kk], bfr, acc[f], 0, 0, 0);
            }
        }
        ushort_t* ho = Hx + ((size_t)((t + 1) & 1) << 18);
        #pragma unroll
        for (int r = 0; r < 4; ++r) {
            int brow = rowbase + lq * 4 + r;
            int tok = goals[brow * 128 + t];
            const ushort_t* gr = G + (size_t)tok * 1536;
            #pragma unroll
            for (int q = 0; q < 2; ++q) {
                int cl = c0 + q * 16 + l16;
                float ir = bf2f(gr[cl]);
                float iz = bf2f(gr[512 + cl]);
                float in_ = bf2f(gr[1024 + cl]);
                float hr = acc[q][r] + bh[0][q];
                float hz = acc[2 + q][r] + bh[1][q];
                float hn = acc[4 + q][r] + bh[2][q];
                float rr = 1.f / (1.f + __expf(-(ir + hr)));
                float zz = 1.f / (1.f + __expf(-(iz + hz)));
                float x = in_ + rr * hn;
                float ax = fabsf(x);
                float th = 1.f - 2.f / (__expf(2.f * ax) + 1.f);
                th = copysignf(th, x);
                float hnew = (1.f - zz) * th + zz * hst[q][r];
                hst[q][r] = hnew;
                ho[(size_t)brow * 512 + cl] = f2bf(hnew);
            }
        }
        // row-group barrier: signal, then wait for the 16 peer blocks
        __threadfence();
        __syncthreads();
        if (tid == 0)
            __hip_atomic_store(&flags[bid], t + 1, __ATOMIC_RELEASE, __HIP_MEMORY_SCOPE_AGENT);
        if (tid < 16) {
            int* pf = &flags[(tid << 4) | rg];
            while (__hip_atomic_load(pf, __ATOMIC_ACQUIRE, __HIP_MEMORY_SCOPE_AGENT) < t + 1)
                __builtin_amdgcn_s_sleep(2);
        }
        __syncthreads();
        __threadfence();
    }

    #pragma unroll
    for (int r = 0; r < 4; ++r) {
        int brow = rowbase + lq * 4 + r;
        #pragma unroll
        for (int q = 0; q < 2; ++q) {
            int cl = c0 + q * 16 + l16;
            goal_out[(size_t)brow * 512 + cl] = hst[q][r];
        }
    }
}

// ---------------- concat: DecA = [bf16(relu(goal)) | R2] ----------------------
__global__ void k_concat(const float* __restrict__ gd, const ushort_t* __restrict__ r2,
                         ushort_t* __restrict__ out) {
    int idx = blockIdx.x * blockDim.x + threadIdx.x;
    if (idx >= 512 * 1024) return;
    int b = idx >> 10, c = idx & 1023;
    out[idx] = (c < 512) ? f2bf(fmaxf(gd[b * 512 + c], 0.f)) : r2[b * 512 + (c - 512)];
}

// ---------------- log_softmax in place, one block per row --------------------
__global__ __launch_bounds__(256) void k_lsm(float* __restrict__ logits) {
    __shared__ float sm[4];
    __shared__ float ss[4];
    float* p = logits + (size_t)blockIdx.x * 1024;
    int tid = threadIdx.x;
    float4 v = ((const float4*)p)[tid];
    float m = fmaxf(fmaxf(v.x, v.y), fmaxf(v.z, v.w));
    #pragma unroll
    for (int o = 32; o >= 1; o >>= 1) m = fmaxf(m, __shfl_xor(m, o));
    if ((tid & 63) == 0) sm[tid >> 6] = m;
    __syncthreads();
    m = fmaxf(fmaxf(sm[0], sm[1]), fmaxf(sm[2], sm[3]));
    float s = __expf(v.x - m) + __expf(v.y - m) + __expf(v.z - m) + __expf(v.w - m);
    #pragma unroll
    for (int o = 32; o >= 1; o >>= 1) s += __shfl_xor(s, o);
    if ((tid & 63) == 0) ss[tid >> 6] = s;
    __syncthreads();
    s = ss[0] + ss[1] + ss[2] + ss[3];
    float lse = m + logf(s);
    v.x -= lse; v.y -= lse; v.z -= lse; v.w -= lse;
    ((float4*)p)[tid] = v;
}

// ---------------- workspace layout -------------------------------------------
static constexpr size_t OFF_G     = 0;                          // 32000x1536 bf16
static constexpr size_t OFF_AREL  = OFF_G     + 98304000ull;    // 32000x512 bf16
static constexpr size_t OFF_WIH   = OFF_AREL  + 32768000ull;    // 1536x512 bf16
static constexpr size_t OFF_WHHF  = OFF_WIH   + 1572864ull;     // frag-ordered
static constexpr size_t OFF_HX    = OFF_WHHF  + 1572864ull;     // 2x512x512 bf16
static constexpr size_t OFF_FLAGS = OFF_HX    + 1048576ull;     // 256 ints
static constexpr size_t OFF_GOAL  = OFF_FLAGS + 1024ull;        // 512x512 f32
static constexpr size_t OFF_FEATS = OFF_GOAL  + 1048576ull;     // 512x512 bf16
static constexpr size_t OFF_W0    = OFF_FEATS + 524288ull;      // 512x512 bf16
static constexpr size_t OFF_W12   = OFF_W0    + 524288ull;      // 2x512x512 bf16
static constexpr size_t OFF_R0    = OFF_W12   + 1048576ull;
static constexpr size_t OFF_R1    = OFF_R0    + 524288ull;
static constexpr size_t OFF_R2    = OFF_R1    + 524288ull;
static constexpr size_t OFF_DECA  = OFF_R2    + 524288ull;      // 512x1024 bf16
static constexpr size_t OFF_WD1   = OFF_DECA  + 1048576ull;     // 512x1024 bf16
static constexpr size_t OFF_D1    = OFF_WD1   + 1048576ull;     // 512x512 bf16
static constexpr size_t OFF_WD2   = OFF_D1    + 524288ull;      // 1024x512 bf16
static constexpr size_t WS_NEED   = OFF_WD2   + 1048576ull;     // ~143.7 MB

extern "C" void kernel_launch(void* const* d_in, const int* in_sizes, int n_in,
                              void* d_out, int out_size, void* d_ws, size_t ws_size,
                              hipStream_t stream) {
    if (ws_size < WS_NEED) return;  // leaves d_out poisoned -> visible failure

    const float* vec   = (const float*)d_in[0];
    const int*   wf    = (const int*)d_in[1];
    const int*   goals = (const int*)d_in[2];
    const float* we0   = (const float*)d_in[3];
    const float* we1   = (const float*)d_in[4];
    const float* we2   = (const float*)d_in[5];
    const float* fiW   = (const float*)d_in[6];
    const float* fib   = (const float*)d_in[7];
    const float* encW  = (const float*)d_in[8];
    const float* encb  = (const float*)d_in[9];
    const float* gemb  = (const float*)d_in[10];
    const float* Wih   = (const float*)d_in[11];
    const float* Whh   = (const float*)d_in[12];
    const float* bih   = (const float*)d_in[13];
    const float* bhh   = (const float*)d_in[14];
    const float* diW   = (const float*)d_in[15];
    const float* dib   = (const float*)d_in[16];
    const float* doW   = (const float*)d_in[17];
    const float* dob   = (const float*)d_in[18];

    char* ws = (char*)d_ws;
    ushort_t* G_     = (ushort_t*)(ws + OFF_G);
    ushort_t* Arel   = (ushort_t*)(ws + OFF_AREL);
    ushort_t* WihB   = (ushort_t*)(ws + OFF_WIH);
    ushort_t* WhhF   = (ushort_t*)(ws + OFF_WHHF);
    ushort_t* Hx     = (ushort_t*)(ws + OFF_HX);
    int*      flags  = (int*)(ws + OFF_FLAGS);
    float*    goalD  = (float*)(ws + OFF_GOAL);
    ushort_t* featsA = (ushort_t*)(ws + OFF_FEATS);
    ushort_t* W0     = (ushort_t*)(ws + OFF_W0);
    ushort_t* W1     = (ushort_t*)(ws + OFF_W12);
    ushort_t* W2     = W1 + 262144;
    ushort_t* R0     = (ushort_t*)(ws + OFF_R0);
    ushort_t* R1     = (ushort_t*)(ws + OFF_R1);
    ushort_t* R2     = (ushort_t*)(ws + OFF_R2);
    ushort_t* DecA   = (ushort_t*)(ws + OFF_DECA);
    ushort_t* Wd1    = (ushort_t*)(ws + OFF_WD1);
    ushort_t* D1     = (ushort_t*)(ws + OFF_D1);
    ushort_t* Wd2    = (ushort_t*)(ws + OFF_WD2);

    // zero Hx (h0 = 0) + flags (must precede k_recur)
    hipMemsetAsync(ws + OFF_HX, 0, 1048576ull + 1024ull, stream);

    auto cgrid = [](int n) { int b = (n / 4 + 255) / 256; return b > 2048 ? 2048 : b; };
    k_conv<false><<<cgrid(786432),  256, 0, stream>>>(Wih,  WihB, 786432);
    k_conv<false><<<cgrid(262144),  256, 0, stream>>>(fiW,  W0,   262144);
    k_conv<false><<<cgrid(524288),  256, 0, stream>>>(encW, W1,   524288);
    k_conv<false><<<cgrid(524288),  256, 0, stream>>>(diW,  Wd1,  524288);
    k_conv<false><<<cgrid(524288),  256, 0, stream>>>(doW,  Wd2,  524288);
    k_conv<true ><<<2048,           256, 0, stream>>>(gemb, Arel, 16384000);
    k_whh_frag<<<3072, 256, 0, stream>>>(Whh, WhhF);
    k_feats<<<1024, 256, 0, stream>>>(vec, wf, we0, we1, we2, featsA);

    // G[v] = relu(emb[v]) @ Wih^T + bih   (32000x1536)
    k_gemm<false, true><<<dim3(12, 250), 256, 0, stream>>>(Arel, WihB, bih, G_, 32000, 1536, 512);

    // features branch: 3 GEMMs with relu epilogue
    k_gemm<true, true><<<dim3(4, 4), 256, 0, stream>>>(featsA, W0, fib,        R0, 512, 512, 512);
    k_gemm<true, true><<<dim3(4, 4), 256, 0, stream>>>(R0,     W1, encb,       R1, 512, 512, 512);
    k_gemm<true, true><<<dim3(4, 4), 256, 0, stream>>>(R1,     W2, encb + 512, R2, 512, 512, 512);

    // GRU recurrence (cooperative: 256 co-resident blocks with flag barriers)
    {
        const ushort_t* Gc = G_; const ushort_t* Wc = WhhF;
        const int* gc = goals; const float* bc = bhh;
        ushort_t* hx = Hx; int* fl = flags; float* go = goalD;
        void* kargs[] = { &Gc, &Wc, &gc, &bc, &hx, &fl, &go };
        hipLaunchCooperativeKernel((const void*)k_recur, dim3(256), dim3(128),
                                   kargs, 0, stream);
    }

    // decoder
    k_concat<<<2048, 256, 0, stream>>>(goalD, R2, DecA);
    k_gemm<true,  true ><<<dim3(4, 4), 256, 0, stream>>>(DecA, Wd1, dib, D1, 512, 512, 1024);
    k_gemm<false, false><<<dim3(8, 4), 256, 0, stream>>>(D1, Wd2, dob, (float*)d_out, 512, 1024, 512);
    k_lsm<<<512, 256, 0, stream>>>((float*)d_out);
}

// Round 5
// 1211.259 us; speedup vs baseline: 3.1491x; 3.1491x over previous
//
#include <hip/hip_runtime.h>
#include <hip/hip_bf16.h>

typedef unsigned short ushort_t;
typedef __attribute__((ext_vector_type(8))) short short8;
typedef __attribute__((ext_vector_type(4))) float f32x4;
typedef __attribute__((ext_vector_type(4))) int i32x4;

__device__ __forceinline__ ushort_t f2bf(float f) {
    unsigned x = __builtin_bit_cast(unsigned, f);
    unsigned r = x + 0x7fffu + ((x >> 16) & 1u);
    return (ushort_t)(r >> 16);
}
__device__ __forceinline__ float bf2f(ushort_t u) {
    return __builtin_bit_cast(float, ((unsigned)u) << 16);
}

// coherent-by-construction accesses: bypass L1+L2, hit memory-side L3 (cross-XCD coherent)
__device__ __forceinline__ void store16_cc(void* p, i32x4 v) {
    asm volatile("global_store_dwordx4 %0, %1, off sc0 sc1" :: "v"(p), "v"(v) : "memory");
}
__device__ __forceinline__ i32x4 load16_cc(const void* p) {
    i32x4 r;
    asm volatile("global_load_dwordx4 %0, %1, off sc0 sc1" : "=v"(r) : "v"(p));
    return r;
}

// ---------------- generic fp32 -> bf16 convert (optional relu) ----------------
template<bool RELU>
__global__ void k_conv(const float* __restrict__ src, ushort_t* __restrict__ dst, int n) {
    int i = (blockIdx.x * blockDim.x + threadIdx.x) * 4;
    int stride = gridDim.x * blockDim.x * 4;
    for (; i < n; i += stride) {
        float4 v = *(const float4*)(src + i);
        if (RELU) {
            v.x = fmaxf(v.x, 0.f); v.y = fmaxf(v.y, 0.f);
            v.z = fmaxf(v.z, 0.f); v.w = fmaxf(v.w, 0.f);
        }
        dst[i + 0] = f2bf(v.x); dst[i + 1] = f2bf(v.y);
        dst[i + 2] = f2bf(v.z); dst[i + 3] = f2bf(v.w);
    }
}

// ---------------- Whh -> fragment-ordered bf16 [16cg][6f][16kk][64lane][8e] ----
__global__ void k_whh_frag(const float* __restrict__ whh, ushort_t* __restrict__ out) {
    int idx = blockIdx.x * blockDim.x + threadIdx.x;
    if (idx >= 16 * 6 * 16 * 64 * 8) return;
    int e  = idx & 7;
    int s  = idx >> 3;
    int l  = s & 63;
    int s2 = s >> 6;
    int kk = s2 & 15;
    int s3 = s2 >> 4;
    int f  = s3 % 6;
    int j  = s3 / 6;
    int ng = (f >> 1) * 512 + j * 32 + (f & 1) * 16 + (l & 15);
    int k  = kk * 32 + ((l >> 4) << 3) + e;
    out[idx] = f2bf(whh[(size_t)ng * 512 + k]);
}

// ---------------- build feats bf16 [512][512] = [vec | e0 | e1 | e2] ----------
__global__ void k_feats(const float* __restrict__ vec, const int* __restrict__ wf,
                        const float* __restrict__ w0, const float* __restrict__ w1,
                        const float* __restrict__ w2, ushort_t* __restrict__ out) {
    int idx = blockIdx.x * blockDim.x + threadIdx.x;
    if (idx >= 512 * 512) return;
    int b = idx >> 9, k = idx & 511;
    float v;
    if (k < 128)       v = vec[b * 128 + k];
    else if (k < 256)  v = w0[wf[b * 3 + 0] * 128 + (k - 128)];
    else if (k < 384)  v = w1[wf[b * 3 + 1] * 128 + (k - 256)];
    else               v = w2[wf[b * 3 + 2] * 128 + (k - 384)];
    out[idx] = f2bf(v);
}

// ---------------- TN MFMA GEMM: C[M,N] = A[M,K](bf16) @ W[N,K]^T + bias -------
template<bool RELU, bool OUTBF>
__global__ __launch_bounds__(256) void k_gemm(const ushort_t* __restrict__ A,
                                              const ushort_t* __restrict__ W,
                                              const float* __restrict__ bias,
                                              void* __restrict__ Cout,
                                              int M, int N, int K) {
    __shared__ __attribute__((aligned(16))) ushort_t As[128 * 64];
    __shared__ __attribute__((aligned(16))) ushort_t Ws[128 * 64];
    const int tid = threadIdx.x;
    const int lane = tid & 63, w = tid >> 6;
    const int wm = w >> 1, wn = w & 1;
    const int m0 = blockIdx.y * 128, n0 = blockIdx.x * 128;
    const int l16 = lane & 15, lq = lane >> 4;
    f32x4 acc[4][4] = {};

    for (int k0 = 0; k0 < K; k0 += 64) {
        #pragma unroll
        for (int c = 0; c < 4; ++c) {
            int chunk = w * 4 + c;
            int d = chunk * 1024 + lane * 16;
            int row = d >> 7;
            int dlin = d ^ ((row & 7) << 4);
            int col = (dlin & 127) >> 1;
            const ushort_t* ga = A + (size_t)(m0 + row) * K + k0 + col;
            __builtin_amdgcn_global_load_lds(
                (const __attribute__((address_space(1))) void*)ga,
                (__attribute__((address_space(3))) void*)(((char*)As) + chunk * 1024),
                16, 0, 0);
        }
        #pragma unroll
        for (int c = 0; c < 4; ++c) {
            int chunk = w * 4 + c;
            int d = chunk * 1024 + lane * 16;
            int row = d >> 7;
            int dlin = d ^ ((row & 7) << 4);
            int col = (dlin & 127) >> 1;
            const ushort_t* gw = W + (size_t)(n0 + row) * K + k0 + col;
            __builtin_amdgcn_global_load_lds(
                (const __attribute__((address_space(1))) void*)gw,
                (__attribute__((address_space(3))) void*)(((char*)Ws) + chunk * 1024),
                16, 0, 0);
        }
        asm volatile("s_waitcnt vmcnt(0)" ::: "memory");
        __syncthreads();

        #pragma unroll
        for (int kk = 0; kk < 2; ++kk) {
            short8 af[4], bfr[4];
            #pragma unroll
            for (int m = 0; m < 4; ++m) {
                int row = wm * 64 + m * 16 + l16;
                int addr = (row * 128 + kk * 64 + lq * 16) ^ ((row & 7) << 4);
                af[m] = *(const short8*)((const char*)As + addr);
            }
            #pragma unroll
            for (int n = 0; n < 4; ++n) {
                int row = wn * 64 + n * 16 + l16;
                int addr = (row * 128 + kk * 64 + lq * 16) ^ ((row & 7) << 4);
                bfr[n] = *(const short8*)((const char*)Ws + addr);
            }
            #pragma unroll
            for (int m = 0; m < 4; ++m)
                #pragma unroll
                for (int n = 0; n < 4; ++n)
                    acc[m][n] = __builtin_amdgcn_mfma_f32_16x16x32_bf16(af[m], bfr[n], acc[m][n], 0, 0, 0);
        }
        __syncthreads();
    }

    #pragma unroll
    for (int m = 0; m < 4; ++m) {
        int row = m0 + wm * 64 + m * 16 + lq * 4;
        #pragma unroll
        for (int n = 0; n < 4; ++n) {
            int col = n0 + wn * 64 + n * 16 + l16;
            float bv = bias[col];
            #pragma unroll
            for (int r = 0; r < 4; ++r) {
                float v = acc[m][n][r] + bv;
                if (RELU) v = fmaxf(v, 0.f);
                if (OUTBF) ((ushort_t*)Cout)[(size_t)(row + r) * N + col] = f2bf(v);
                else       ((float*)Cout)[(size_t)(row + r) * N + col] = v;
            }
        }
    }
}

// ---------------- GRU recurrence: persistent cooperative, 256 blocks ---------
// block b: row-group rg=b&15 (32 batch rows), col-group cg=b>>4 (32 hid cols).
// Whh slice fragment-ordered in LDS. Hidden state exchanged via DOUBLE-BUFFERED
// global Hx using ONLY sc0/sc1 (L1+L2-bypassing, memory-side-coherent) accesses
// -> no threadfence / no L2 writeback-invalidate per step. Flags: relaxed
// agent-scope atomics (coherence-point ops). h0 == 0 handled by skipping the
// h-read at t=0. Spin is BOUNDED (~100k sleeps): a wrong coherence model
// produces a terminating absmax failure instead of a GPU hang.
__global__ __launch_bounds__(128) void k_recur(const ushort_t* __restrict__ G,
                                               const ushort_t* __restrict__ WhhF,
                                               const int* __restrict__ goals,
                                               const float* __restrict__ bhh,
                                               ushort_t* __restrict__ Hx,
                                               int* __restrict__ flags,
                                               float* __restrict__ goal_out) {
    __shared__ __attribute__((aligned(16))) ushort_t Bs[6 * 16 * 64 * 8]; // 98304 B
    __shared__ __attribute__((aligned(16))) ushort_t Hs[32 * 32];         // 2 KB
    const int bid = blockIdx.x;
    const int rg = bid & 15;
    const int cg = bid >> 4;
    const int r0 = rg * 32, c0 = cg * 32;
    const int tid = threadIdx.x, lane = tid & 63, w = tid >> 6;
    const int l16 = lane & 15, lq = lane >> 4;

    // load Whh fragment slice: 98304B = 96 chunks of 1KB
    {
        const ushort_t* src = WhhF + (size_t)cg * 49152;
        for (int c = 0; c < 48; ++c) {
            int chunk = w * 48 + c;
            const ushort_t* ga = src + chunk * 512 + lane * 8;
            __builtin_amdgcn_global_load_lds(
                (const __attribute__((address_space(1))) void*)ga,
                (__attribute__((address_space(3))) void*)(((char*)Bs) + chunk * 1024),
                16, 0, 0);
        }
        asm volatile("s_waitcnt vmcnt(0)" ::: "memory");
        __syncthreads();
    }

    const int rowbase = r0 + w * 16;
    float hst[2][4];
    #pragma unroll
    for (int q = 0; q < 2; ++q)
        #pragma unroll
        for (int r = 0; r < 4; ++r) hst[q][r] = 0.f;

    float bh[3][2];
    #pragma unroll
    for (int g = 0; g < 3; ++g)
        #pragma unroll
        for (int q = 0; q < 2; ++q) bh[g][q] = bhh[g * 512 + c0 + q * 16 + l16];

    for (int t = 0; t < 128; ++t) {
        // A) G gathers (independent of h) — normal cached loads
        float gir[4][2], giz[4][2], gin[4][2];
        #pragma unroll
        for (int r = 0; r < 4; ++r) {
            int brow = rowbase + lq * 4 + r;
            int tok = goals[brow * 128 + t];
            const ushort_t* gr = G + (size_t)tok * 1536;
            #pragma unroll
            for (int q = 0; q < 2; ++q) {
                int cl = c0 + q * 16 + l16;
                gir[r][q] = bf2f(gr[cl]);
                giz[r][q] = bf2f(gr[512 + cl]);
                gin[r][q] = bf2f(gr[1024 + cl]);
            }
        }

        // B) h-tile load (sc0 sc1) + MFMA; t==0 has h=0 -> acc stays 0
        f32x4 acc[6] = {};
        if (t) {
            const ushort_t* hb = Hx + ((size_t)(t & 1) << 18);
            short8 af[16];
            #pragma unroll
            for (int kk = 0; kk < 16; ++kk) {
                const ushort_t* pa = hb + (size_t)(rowbase + l16) * 512 + kk * 32 + lq * 8;
                af[kk] = __builtin_bit_cast(short8, load16_cc(pa));
            }
            asm volatile("s_waitcnt vmcnt(0)" ::: "memory");
            __builtin_amdgcn_sched_barrier(0);
            #pragma unroll
            for (int kk = 0; kk < 16; ++kk) {
                #pragma unroll
                for (int f = 0; f < 6; ++f) {
                    short8 bfr = *(const short8*)((const char*)Bs + ((f * 16 + kk) * 64 + lane) * 16);
                    acc[f] = __builtin_amdgcn_mfma_f32_16x16x32_bf16(af[kk], bfr, acc[f], 0, 0, 0);
                }
            }
        }

        // C) gates + state update; write tile into LDS for vectorized store
        #pragma unroll
        for (int r = 0; r < 4; ++r) {
            #pragma unroll
            for (int q = 0; q < 2; ++q) {
                float ir = gir[r][q], iz = giz[r][q], in_ = gin[r][q];
                float hr = acc[q][r] + bh[0][q];
                float hz = acc[2 + q][r] + bh[1][q];
                float hn = acc[4 + q][r] + bh[2][q];
                float rr = 1.f / (1.f + __expf(-(ir + hr)));
                float zz = 1.f / (1.f + __expf(-(iz + hz)));
                float x = in_ + rr * hn;
                float ax = fabsf(x);
                float th = 1.f - 2.f / (__expf(2.f * ax) + 1.f);
                th = copysignf(th, x);
                float hnew = (1.f - zz) * th + zz * hst[q][r];
                hst[q][r] = hnew;
                Hs[(w * 16 + lq * 4 + r) * 32 + q * 16 + l16] = f2bf(hnew);
            }
        }
        __syncthreads();

        // D) vectorized coherent store of the 32x32 tile (16B per thread)
        {
            int row = tid >> 2, coff = (tid & 3) * 8;
            i32x4 v = *(const i32x4*)&Hs[row * 32 + coff];
            ushort_t* ho = Hx + ((size_t)((t + 1) & 1) << 18)
                         + (size_t)(r0 + row) * 512 + c0 + coff;
            store16_cc(ho, v);
        }
        asm volatile("s_waitcnt vmcnt(0)" ::: "memory");
        __syncthreads();   // all waves' stores drained before flag release

        // E) row-group flag barrier (relaxed agent atomics, BOUNDED spin)
        if (tid == 0)
            __hip_atomic_store(&flags[bid], t + 1, __ATOMIC_RELAXED, __HIP_MEMORY_SCOPE_AGENT);
        if (tid < 16) {
            int* pf = &flags[(tid << 4) | rg];
            for (int it = 0; it < 100000; ++it) {
                if (__hip_atomic_load(pf, __ATOMIC_RELAXED, __HIP_MEMORY_SCOPE_AGENT) >= t + 1)
                    break;
                __builtin_amdgcn_s_sleep(1);
            }
        }
        __syncthreads();
    }

    #pragma unroll
    for (int r = 0; r < 4; ++r) {
        int brow = rowbase + lq * 4 + r;
        #pragma unroll
        for (int q = 0; q < 2; ++q) {
            int cl = c0 + q * 16 + l16;
            goal_out[(size_t)brow * 512 + cl] = hst[q][r];
        }
    }
}

// ---------------- concat: DecA = [bf16(relu(goal)) | R2] ----------------------
__global__ void k_concat(const float* __restrict__ gd, const ushort_t* __restrict__ r2,
                         ushort_t* __restrict__ out) {
    int idx = blockIdx.x * blockDim.x + threadIdx.x;
    if (idx >= 512 * 1024) return;
    int b = idx >> 10, c = idx & 1023;
    out[idx] = (c < 512) ? f2bf(fmaxf(gd[b * 512 + c], 0.f)) : r2[b * 512 + (c - 512)];
}

// ---------------- log_softmax in place, one block per row --------------------
__global__ __launch_bounds__(256) void k_lsm(float* __restrict__ logits) {
    __shared__ float sm[4];
    __shared__ float ss[4];
    float* p = logits + (size_t)blockIdx.x * 1024;
    int tid = threadIdx.x;
    float4 v = ((const float4*)p)[tid];
    float m = fmaxf(fmaxf(v.x, v.y), fmaxf(v.z, v.w));
    #pragma unroll
    for (int o = 32; o >= 1; o >>= 1) m = fmaxf(m, __shfl_xor(m, o));
    if ((tid & 63) == 0) sm[tid >> 6] = m;
    __syncthreads();
    m = fmaxf(fmaxf(sm[0], sm[1]), fmaxf(sm[2], sm[3]));
    float s = __expf(v.x - m) + __expf(v.y - m) + __expf(v.z - m) + __expf(v.w - m);
    #pragma unroll
    for (int o = 32; o >= 1; o >>= 1) s += __shfl_xor(s, o);
    if ((tid & 63) == 0) ss[tid >> 6] = s;
    __syncthreads();
    s = ss[0] + ss[1] + ss[2] + ss[3];
    float lse = m + logf(s);
    v.x -= lse; v.y -= lse; v.z -= lse; v.w -= lse;
    ((float4*)p)[tid] = v;
}

// ---------------- workspace layout -------------------------------------------
static constexpr size_t OFF_G     = 0;                          // 32000x1536 bf16
static constexpr size_t OFF_AREL  = OFF_G     + 98304000ull;    // 32000x512 bf16
static constexpr size_t OFF_WIH   = OFF_AREL  + 32768000ull;    // 1536x512 bf16
static constexpr size_t OFF_WHHF  = OFF_WIH   + 1572864ull;     // frag-ordered
static constexpr size_t OFF_HX    = OFF_WHHF  + 1572864ull;     // 2x512x512 bf16
static constexpr size_t OFF_FLAGS = OFF_HX    + 1048576ull;     // 256 ints
static constexpr size_t OFF_GOAL  = OFF_FLAGS + 1024ull;        // 512x512 f32
static constexpr size_t OFF_FEATS = OFF_GOAL  + 1048576ull;     // 512x512 bf16
static constexpr size_t OFF_W0    = OFF_FEATS + 524288ull;      // 512x512 bf16
static constexpr size_t OFF_W12   = OFF_W0    + 524288ull;      // 2x512x512 bf16
static constexpr size_t OFF_R0    = OFF_W12   + 1048576ull;
static constexpr size_t OFF_R1    = OFF_R0    + 524288ull;
static constexpr size_t OFF_R2    = OFF_R1    + 524288ull;
static constexpr size_t OFF_DECA  = OFF_R2    + 524288ull;      // 512x1024 bf16
static constexpr size_t OFF_WD1   = OFF_DECA  + 1048576ull;     // 512x1024 bf16
static constexpr size_t OFF_D1    = OFF_WD1   + 1048576ull;     // 512x512 bf16
static constexpr size_t OFF_WD2   = OFF_D1    + 524288ull;      // 1024x512 bf16
static constexpr size_t WS_NEED   = OFF_WD2   + 1048576ull;     // ~143.7 MB

extern "C" void kernel_launch(void* const* d_in, const int* in_sizes, int n_in,
                              void* d_out, int out_size, void* d_ws, size_t ws_size,
                              hipStream_t stream) {
    if (ws_size < WS_NEED) return;  // leaves d_out poisoned -> visible failure

    const float* vec   = (const float*)d_in[0];
    const int*   wf    = (const int*)d_in[1];
    const int*   goals = (const int*)d_in[2];
    const float* we0   = (const float*)d_in[3];
    const float* we1   = (const float*)d_in[4];
    const float* we2   = (const float*)d_in[5];
    const float* fiW   = (const float*)d_in[6];
    const float* fib   = (const float*)d_in[7];
    const float* encW  = (const float*)d_in[8];
    const float* encb  = (const float*)d_in[9];
    const float* gemb  = (const float*)d_in[10];
    const float* Wih   = (const float*)d_in[11];
    const float* Whh   = (const float*)d_in[12];
    const float* bih   = (const float*)d_in[13];
    const float* bhh   = (const float*)d_in[14];
    const float* diW   = (const float*)d_in[15];
    const float* dib   = (const float*)d_in[16];
    const float* doW   = (const float*)d_in[17];
    const float* dob   = (const float*)d_in[18];

    char* ws = (char*)d_ws;
    ushort_t* G_     = (ushort_t*)(ws + OFF_G);
    ushort_t* Arel   = (ushort_t*)(ws + OFF_AREL);
    ushort_t* WihB   = (ushort_t*)(ws + OFF_WIH);
    ushort_t* WhhF   = (ushort_t*)(ws + OFF_WHHF);
    ushort_t* Hx     = (ushort_t*)(ws + OFF_HX);
    int*      flags  = (int*)(ws + OFF_FLAGS);
    float*    goalD  = (float*)(ws + OFF_GOAL);
    ushort_t* featsA = (ushort_t*)(ws + OFF_FEATS);
    ushort_t* W0     = (ushort_t*)(ws + OFF_W0);
    ushort_t* W1     = (ushort_t*)(ws + OFF_W12);
    ushort_t* W2     = W1 + 262144;
    ushort_t* R0     = (ushort_t*)(ws + OFF_R0);
    ushort_t* R1     = (ushort_t*)(ws + OFF_R1);
    ushort_t* R2     = (ushort_t*)(ws + OFF_R2);
    ushort_t* DecA   = (ushort_t*)(ws + OFF_DECA);
    ushort_t* Wd1    = (ushort_t*)(ws + OFF_WD1);
    ushort_t* D1     = (ushort_t*)(ws + OFF_D1);
    ushort_t* Wd2    = (ushort_t*)(ws + OFF_WD2);

    // zero flags only (kernel-boundary flush makes these visible to atomics).
    // Hx needs NO init: t=0 skips the h-read (h0 == 0).
    hipMemsetAsync(ws + OFF_FLAGS, 0, 1024, stream);

    auto cgrid = [](int n) { int b = (n / 4 + 255) / 256; return b > 2048 ? 2048 : b; };
    k_conv<false><<<cgrid(786432),  256, 0, stream>>>(Wih,  WihB, 786432);
    k_conv<false><<<cgrid(262144),  256, 0, stream>>>(fiW,  W0,   262144);
    k_conv<false><<<cgrid(524288),  256, 0, stream>>>(encW, W1,   524288);
    k_conv<false><<<cgrid(524288),  256, 0, stream>>>(diW,  Wd1,  524288);
    k_conv<false><<<cgrid(524288),  256, 0, stream>>>(doW,  Wd2,  524288);
    k_conv<true ><<<2048,           256, 0, stream>>>(gemb, Arel, 16384000);
    k_whh_frag<<<3072, 256, 0, stream>>>(Whh, WhhF);
    k_feats<<<1024, 256, 0, stream>>>(vec, wf, we0, we1, we2, featsA);

    // G[v] = relu(emb[v]) @ Wih^T + bih   (32000x1536)
    k_gemm<false, true><<<dim3(12, 250), 256, 0, stream>>>(Arel, WihB, bih, G_, 32000, 1536, 512);

    // features branch: 3 GEMMs with relu epilogue
    k_gemm<true, true><<<dim3(4, 4), 256, 0, stream>>>(featsA, W0, fib,        R0, 512, 512, 512);
    k_gemm<true, true><<<dim3(4, 4), 256, 0, stream>>>(R0,     W1, encb,       R1, 512, 512, 512);
    k_gemm<true, true><<<dim3(4, 4), 256, 0, stream>>>(R1,     W2, encb + 512, R2, 512, 512, 512);

    // GRU recurrence (cooperative: 256 co-resident blocks with flag barriers)
    {
        const ushort_t* Gc = G_; const ushort_t* Wc = WhhF;
        const int* gc = goals; const float* bc = bhh;
        ushort_t* hx = Hx; int* fl = flags; float* go = goalD;
        void* kargs[] = { &Gc, &Wc, &gc, &bc, &hx, &fl, &go };
        hipLaunchCooperativeKernel((const void*)k_recur, dim3(256), dim3(128),
                                   kargs, 0, stream);
    }

    // decoder
    k_concat<<<2048, 256, 0, stream>>>(goalD, R2, DecA);
    k_gemm<true,  true ><<<dim3(4, 4), 256, 0, stream>>>(DecA, Wd1, dib, D1, 512, 512, 1024);
    k_gemm<false, false><<<dim3(8, 4), 256, 0, stream>>>(D1, Wd2, dob, (float*)d_out, 512, 1024, 512);
    k_lsm<<<512, 256, 0, stream>>>((float*)d_out);
}

// Round 8
// 1172.631 us; speedup vs baseline: 3.2528x; 1.0329x over previous
//
#include <hip/hip_runtime.h>
#include <hip/hip_bf16.h>

typedef unsigned short ushort_t;
typedef __attribute__((ext_vector_type(8))) short short8;
typedef __attribute__((ext_vector_type(4))) float f32x4;
typedef __attribute__((ext_vector_type(4))) int i32x4;

__device__ __forceinline__ ushort_t f2bf(float f) {
    unsigned x = __builtin_bit_cast(unsigned, f);
    unsigned r = x + 0x7fffu + ((x >> 16) & 1u);
    return (ushort_t)(r >> 16);
}
__device__ __forceinline__ float bf2f(ushort_t u) {
    return __builtin_bit_cast(float, ((unsigned)u) << 16);
}

// coherent-by-construction accesses: bypass L1+L2, hit memory-side L3 (cross-XCD coherent)
__device__ __forceinline__ void store16_cc(void* p, i32x4 v) {
    asm volatile("global_store_dwordx4 %0, %1, off sc0 sc1" :: "v"(p), "v"(v) : "memory");
}
__device__ __forceinline__ i32x4 load16_cc(const void* p) {
    i32x4 r;
    asm volatile("global_load_dwordx4 %0, %1, off sc0 sc1" : "=v"(r) : "v"(p));
    return r;
}
// raw u16 load, NO implicit wait — caller must s_waitcnt before reading result
__device__ __forceinline__ unsigned load_u16_raw(const ushort_t* p) {
    unsigned r;
    asm volatile("global_load_ushort %0, %1, off" : "=v"(r) : "v"(p));
    return r;
}

// ---------------- generic fp32 -> bf16 convert (optional relu) ----------------
template<bool RELU>
__global__ void k_conv(const float* __restrict__ src, ushort_t* __restrict__ dst, int n) {
    int i = (blockIdx.x * blockDim.x + threadIdx.x) * 4;
    int stride = gridDim.x * blockDim.x * 4;
    for (; i < n; i += stride) {
        float4 v = *(const float4*)(src + i);
        if (RELU) {
            v.x = fmaxf(v.x, 0.f); v.y = fmaxf(v.y, 0.f);
            v.z = fmaxf(v.z, 0.f); v.w = fmaxf(v.w, 0.f);
        }
        dst[i + 0] = f2bf(v.x); dst[i + 1] = f2bf(v.y);
        dst[i + 2] = f2bf(v.z); dst[i + 3] = f2bf(v.w);
    }
}

// ---------------- Whh -> fragment-ordered bf16 [16cg][6f][16kk][64lane][8e] ----
__global__ void k_whh_frag(const float* __restrict__ whh, ushort_t* __restrict__ out) {
    int idx = blockIdx.x * blockDim.x + threadIdx.x;
    if (idx >= 16 * 6 * 16 * 64 * 8) return;
    int e  = idx & 7;
    int s  = idx >> 3;
    int l  = s & 63;
    int s2 = s >> 6;
    int kk = s2 & 15;
    int s3 = s2 >> 4;
    int f  = s3 % 6;
    int j  = s3 / 6;
    int ng = (f >> 1) * 512 + j * 32 + (f & 1) * 16 + (l & 15);
    int k  = kk * 32 + ((l >> 4) << 3) + e;
    out[idx] = f2bf(whh[(size_t)ng * 512 + k]);
}

// ---------------- build feats bf16 [512][512] = [vec | e0 | e1 | e2] ----------
__global__ void k_feats(const float* __restrict__ vec, const int* __restrict__ wf,
                        const float* __restrict__ w0, const float* __restrict__ w1,
                        const float* __restrict__ w2, ushort_t* __restrict__ out) {
    int idx = blockIdx.x * blockDim.x + threadIdx.x;
    if (idx >= 512 * 512) return;
    int b = idx >> 9, k = idx & 511;
    float v;
    if (k < 128)       v = vec[b * 128 + k];
    else if (k < 256)  v = w0[wf[b * 3 + 0] * 128 + (k - 128)];
    else if (k < 384)  v = w1[wf[b * 3 + 1] * 128 + (k - 256)];
    else               v = w2[wf[b * 3 + 2] * 128 + (k - 384)];
    out[idx] = f2bf(v);
}

// ---------------- TN MFMA GEMM: C[M,N] = A[M,K](bf16) @ W[N,K]^T + bias -------
template<bool RELU, bool OUTBF>
__global__ __launch_bounds__(256) void k_gemm(const ushort_t* __restrict__ A,
                                              const ushort_t* __restrict__ W,
                                              const float* __restrict__ bias,
                                              void* __restrict__ Cout,
                                              int M, int N, int K) {
    __shared__ __attribute__((aligned(16))) ushort_t As[128 * 64];
    __shared__ __attribute__((aligned(16))) ushort_t Ws[128 * 64];
    const int tid = threadIdx.x;
    const int lane = tid & 63, w = tid >> 6;
    const int wm = w >> 1, wn = w & 1;
    const int m0 = blockIdx.y * 128, n0 = blockIdx.x * 128;
    const int l16 = lane & 15, lq = lane >> 4;
    f32x4 acc[4][4] = {};

    for (int k0 = 0; k0 < K; k0 += 64) {
        #pragma unroll
        for (int c = 0; c < 4; ++c) {
            int chunk = w * 4 + c;
            int d = chunk * 1024 + lane * 16;
            int row = d >> 7;
            int dlin = d ^ ((row & 7) << 4);
            int col = (dlin & 127) >> 1;
            const ushort_t* ga = A + (size_t)(m0 + row) * K + k0 + col;
            __builtin_amdgcn_global_load_lds(
                (const __attribute__((address_space(1))) void*)ga,
                (__attribute__((address_space(3))) void*)(((char*)As) + chunk * 1024),
                16, 0, 0);
        }
        #pragma unroll
        for (int c = 0; c < 4; ++c) {
            int chunk = w * 4 + c;
            int d = chunk * 1024 + lane * 16;
            int row = d >> 7;
            int dlin = d ^ ((row & 7) << 4);
            int col = (dlin & 127) >> 1;
            const ushort_t* gw = W + (size_t)(n0 + row) * K + k0 + col;
            __builtin_amdgcn_global_load_lds(
                (const __attribute__((address_space(1))) void*)gw,
                (__attribute__((address_space(3))) void*)(((char*)Ws) + chunk * 1024),
                16, 0, 0);
        }
        asm volatile("s_waitcnt vmcnt(0)" ::: "memory");
        __syncthreads();

        #pragma unroll
        for (int kk = 0; kk < 2; ++kk) {
            short8 af[4], bfr[4];
            #pragma unroll
            for (int m = 0; m < 4; ++m) {
                int row = wm * 64 + m * 16 + l16;
                int addr = (row * 128 + kk * 64 + lq * 16) ^ ((row & 7) << 4);
                af[m] = *(const short8*)((const char*)As + addr);
            }
            #pragma unroll
            for (int n = 0; n < 4; ++n) {
                int row = wn * 64 + n * 16 + l16;
                int addr = (row * 128 + kk * 64 + lq * 16) ^ ((row & 7) << 4);
                bfr[n] = *(const short8*)((const char*)Ws + addr);
            }
            #pragma unroll
            for (int m = 0; m < 4; ++m)
                #pragma unroll
                for (int n = 0; n < 4; ++n)
                    acc[m][n] = __builtin_amdgcn_mfma_f32_16x16x32_bf16(af[m], bfr[n], acc[m][n], 0, 0, 0);
        }
        __syncthreads();
    }

    #pragma unroll
    for (int m = 0; m < 4; ++m) {
        int row = m0 + wm * 64 + m * 16 + lq * 4;
        #pragma unroll
        for (int n = 0; n < 4; ++n) {
            int col = n0 + wn * 64 + n * 16 + l16;
            float bv = bias[col];
            #pragma unroll
            for (int r = 0; r < 4; ++r) {
                float v = acc[m][n][r] + bv;
                if (RELU) v = fmaxf(v, 0.f);
                if (OUTBF) ((ushort_t*)Cout)[(size_t)(row + r) * N + col] = f2bf(v);
                else       ((float*)Cout)[(size_t)(row + r) * N + col] = v;
            }
        }
    }
}

// ---------------- GRU recurrence: persistent cooperative, 256 blocks ---------
// block b: rg=b&15 (32 batch rows), cg=b>>4 (32 hid cols). Whh slice in LDS.
// h exchanged via double-buffered Hx using sc0/sc1 accesses (no fences).
// Tokens staged to LDS once; G gate-values PREFETCHED one step ahead into
// registers (24 raw u16 loads issued after the 16 h-loads; counted wait
// vmcnt(24) releases MFMA when h lands, prefetch drains at end-of-step
// vmcnt(0)). Removes the ~2 us/step serial HBM-gather chain from the
// critical path.
__global__ __launch_bounds__(128) void k_recur(const ushort_t* __restrict__ G,
                                               const ushort_t* __restrict__ WhhF,
                                               const int* __restrict__ goals,
                                               const float* __restrict__ bhh,
                                               ushort_t* __restrict__ Hx,
                                               int* __restrict__ flags,
                                               float* __restrict__ goal_out) {
    __shared__ __attribute__((aligned(16))) ushort_t Bs[6 * 16 * 64 * 8]; // 98304 B
    __shared__ __attribute__((aligned(16))) ushort_t Hs[32 * 32];         // 2 KB
    __shared__ __attribute__((aligned(16))) int Tk[32 * 128];             // 16 KB tokens
    const int bid = blockIdx.x;
    const int rg = bid & 15;
    const int cg = bid >> 4;
    const int r0 = rg * 32, c0 = cg * 32;
    const int tid = threadIdx.x, lane = tid & 63, w = tid >> 6;
    const int l16 = lane & 15, lq = lane >> 4;

    // stage Whh fragment slice (96 KB) + token slab (16 KB) in one pass
    {
        const ushort_t* src = WhhF + (size_t)cg * 49152;
        for (int c = 0; c < 48; ++c) {
            int chunk = w * 48 + c;
            __builtin_amdgcn_global_load_lds(
                (const __attribute__((address_space(1))) void*)(src + chunk * 512 + lane * 8),
                (__attribute__((address_space(3))) void*)(((char*)Bs) + chunk * 1024),
                16, 0, 0);
        }
        const int* tsrc = goals + r0 * 128;   // 32 contiguous rows x 128 ints
        for (int c = 0; c < 8; ++c) {
            int chunk = w * 8 + c;
            __builtin_amdgcn_global_load_lds(
                (const __attribute__((address_space(1))) void*)(tsrc + chunk * 256 + lane * 4),
                (__attribute__((address_space(3))) void*)(((char*)Tk) + chunk * 1024),
                16, 0, 0);
        }
        asm volatile("s_waitcnt vmcnt(0)" ::: "memory");
        __syncthreads();
    }

    const int rowbase = r0 + w * 16;
    const int lrow = w * 16 + lq * 4;          // local row base for this thread
    float hst[2][4];
    #pragma unroll
    for (int q = 0; q < 2; ++q)
        #pragma unroll
        for (int r = 0; r < 4; ++r) hst[q][r] = 0.f;

    float bh[3][2];
    #pragma unroll
    for (int g = 0; g < 3; ++g)
        #pragma unroll
        for (int q = 0; q < 2; ++q) bh[g][q] = bhh[g * 512 + c0 + q * 16 + l16];

    // prologue: G gate values for t=0 (normal cached loads)
    float gc[3][4][2];
    #pragma unroll
    for (int r = 0; r < 4; ++r) {
        int tok = Tk[(lrow + r) * 128];
        const ushort_t* gr = G + (size_t)tok * 1536;
        #pragma unroll
        for (int q = 0; q < 2; ++q) {
            int cl = c0 + q * 16 + l16;
            gc[0][r][q] = bf2f(gr[cl]);
            gc[1][r][q] = bf2f(gr[512 + cl]);
            gc[2][r][q] = bf2f(gr[1024 + cl]);
        }
    }

    unsigned gn[3][4][2];
    auto issueGN = [&](int tn) {
        #pragma unroll
        for (int r = 0; r < 4; ++r) {
            int tok = Tk[(lrow + r) * 128 + tn];
            const ushort_t* gr = G + (size_t)tok * 1536;
            #pragma unroll
            for (int q = 0; q < 2; ++q) {
                int cl = c0 + q * 16 + l16;
                gn[0][r][q] = load_u16_raw(gr + cl);
                gn[1][r][q] = load_u16_raw(gr + 512 + cl);
                gn[2][r][q] = load_u16_raw(gr + 1024 + cl);
            }
        }
    };

    for (int t = 0; t < 128; ++t) {
        const int tn = (t < 127) ? t + 1 : 127;
        f32x4 acc[6] = {};
        if (t) {
            // 16 h sc-loads FIRST (oldest), then 24 prefetch loads
            const ushort_t* hb = Hx + ((size_t)(t & 1) << 18);
            short8 af[16];
            #pragma unroll
            for (int kk = 0; kk < 16; ++kk) {
                const ushort_t* pa = hb + (size_t)(rowbase + l16) * 512 + kk * 32 + lq * 8;
                af[kk] = __builtin_bit_cast(short8, load16_cc(pa));
            }
            issueGN(tn);
            // wait only for the 16 h-loads (oldest); prefetch stays in flight
            asm volatile("s_waitcnt vmcnt(24)" ::: "memory");
            __builtin_amdgcn_sched_barrier(0);
            #pragma unroll
            for (int kk = 0; kk < 16; ++kk) {
                #pragma unroll
                for (int f = 0; f < 6; ++f) {
                    short8 bfr = *(const short8*)((const char*)Bs + ((f * 16 + kk) * 64 + lane) * 16);
                    acc[f] = __builtin_amdgcn_mfma_f32_16x16x32_bf16(af[kk], bfr, acc[f], 0, 0, 0);
                }
            }
        } else {
            issueGN(tn);
        }

        // gates + state update using gc (prefetched last step); stage into LDS
        #pragma unroll
        for (int r = 0; r < 4; ++r) {
            #pragma unroll
            for (int q = 0; q < 2; ++q) {
                float ir = gc[0][r][q], iz = gc[1][r][q], in_ = gc[2][r][q];
                float hr = acc[q][r] + bh[0][q];
                float hz = acc[2 + q][r] + bh[1][q];
                float hn = acc[4 + q][r] + bh[2][q];
                float rr = 1.f / (1.f + __expf(-(ir + hr)));
                float zz = 1.f / (1.f + __expf(-(iz + hz)));
                float x = in_ + rr * hn;
                float ax = fabsf(x);
                float th = 1.f - 2.f / (__expf(2.f * ax) + 1.f);
                th = copysignf(th, x);
                float hnew = (1.f - zz) * th + zz * hst[q][r];
                hst[q][r] = hnew;
                Hs[(w * 16 + lq * 4 + r) * 32 + q * 16 + l16] = f2bf(hnew);
            }
        }
        __syncthreads();

        // vectorized coherent store of the 32x32 tile (16B per thread)
        {
            int row = tid >> 2, coff = (tid & 3) * 8;
            i32x4 v = *(const i32x4*)&Hs[row * 32 + coff];
            ushort_t* ho = Hx + ((size_t)((t + 1) & 1) << 18)
                         + (size_t)(r0 + row) * 512 + c0 + coff;
            store16_cc(ho, v);
        }
        asm volatile("s_waitcnt vmcnt(0)" ::: "memory");  // drains store + prefetch
        __builtin_amdgcn_sched_barrier(0);
        __syncthreads();

        // row-group flag barrier (relaxed agent atomics, BOUNDED spin)
        if (tid == 0)
            __hip_atomic_store(&flags[bid], t + 1, __ATOMIC_RELAXED, __HIP_MEMORY_SCOPE_AGENT);
        if (tid < 16) {
            int* pf = &flags[(tid << 4) | rg];
            for (int it = 0; it < 100000; ++it) {
                if (__hip_atomic_load(pf, __ATOMIC_RELAXED, __HIP_MEMORY_SCOPE_AGENT) >= t + 1)
                    break;
                __builtin_amdgcn_s_sleep(1);
            }
        }
        __syncthreads();

        // rotate prefetched raw values into gc (loads drained by vmcnt(0) above)
        #pragma unroll
        for (int g = 0; g < 3; ++g)
            #pragma unroll
            for (int r = 0; r < 4; ++r)
                #pragma unroll
                for (int q = 0; q < 2; ++q)
                    gc[g][r][q] = bf2f((ushort_t)gn[g][r][q]);
    }

    #pragma unroll
    for (int r = 0; r < 4; ++r) {
        int brow = rowbase + lq * 4 + r;
        #pragma unroll
        for (int q = 0; q < 2; ++q) {
            int cl = c0 + q * 16 + l16;
            goal_out[(size_t)brow * 512 + cl] = hst[q][r];
        }
    }
}

// ---------------- concat: DecA = [bf16(relu(goal)) | R2] ----------------------
__global__ void k_concat(const float* __restrict__ gd, const ushort_t* __restrict__ r2,
                         ushort_t* __restrict__ out) {
    int idx = blockIdx.x * blockDim.x + threadIdx.x;
    if (idx >= 512 * 1024) return;
    int b = idx >> 10, c = idx & 1023;
    out[idx] = (c < 512) ? f2bf(fmaxf(gd[b * 512 + c], 0.f)) : r2[b * 512 + (c - 512)];
}

// ---------------- log_softmax in place, one block per row --------------------
__global__ __launch_bounds__(256) void k_lsm(float* __restrict__ logits) {
    __shared__ float sm[4];
    __shared__ float ss[4];
    float* p = logits + (size_t)blockIdx.x * 1024;
    int tid = threadIdx.x;
    float4 v = ((const float4*)p)[tid];
    float m = fmaxf(fmaxf(v.x, v.y), fmaxf(v.z, v.w));
    #pragma unroll
    for (int o = 32; o >= 1; o >>= 1) m = fmaxf(m, __shfl_xor(m, o));
    if ((tid & 63) == 0) sm[tid >> 6] = m;
    __syncthreads();
    m = fmaxf(fmaxf(sm[0], sm[1]), fmaxf(sm[2], sm[3]));
    float s = __expf(v.x - m) + __expf(v.y - m) + __expf(v.z - m) + __expf(v.w - m);
    #pragma unroll
    for (int o = 32; o >= 1; o >>= 1) s += __shfl_xor(s, o);
    if ((tid & 63) == 0) ss[tid >> 6] = s;
    __syncthreads();
    s = ss[0] + ss[1] + ss[2] + ss[3];
    float lse = m + logf(s);
    v.x -= lse; v.y -= lse; v.z -= lse; v.w -= lse;
    ((float4*)p)[tid] = v;
}

// ---------------- workspace layout -------------------------------------------
static constexpr size_t OFF_G     = 0;                          // 32000x1536 bf16
static constexpr size_t OFF_AREL  = OFF_G     + 98304000ull;    // 32000x512 bf16
static constexpr size_t OFF_WIH   = OFF_AREL  + 32768000ull;    // 1536x512 bf16
static constexpr size_t OFF_WHHF  = OFF_WIH   + 1572864ull;     // frag-ordered
static constexpr size_t OFF_HX    = OFF_WHHF  + 1572864ull;     // 2x512x512 bf16
static constexpr size_t OFF_FLAGS = OFF_HX    + 1048576ull;     // 256 ints
static constexpr size_t OFF_GOAL  = OFF_FLAGS + 1024ull;        // 512x512 f32
static constexpr size_t OFF_FEATS = OFF_GOAL  + 1048576ull;     // 512x512 bf16
static constexpr size_t OFF_W0    = OFF_FEATS + 524288ull;      // 512x512 bf16
static constexpr size_t OFF_W12   = OFF_W0    + 524288ull;      // 2x512x512 bf16
static constexpr size_t OFF_R0    = OFF_W12   + 1048576ull;
static constexpr size_t OFF_R1    = OFF_R0    + 524288ull;
static constexpr size_t OFF_R2    = OFF_R1    + 524288ull;
static constexpr size_t OFF_DECA  = OFF_R2    + 524288ull;      // 512x1024 bf16
static constexpr size_t OFF_WD1   = OFF_DECA  + 1048576ull;     // 512x1024 bf16
static constexpr size_t OFF_D1    = OFF_WD1   + 1048576ull;     // 512x512 bf16
static constexpr size_t OFF_WD2   = OFF_D1    + 524288ull;      // 1024x512 bf16
static constexpr size_t WS_NEED   = OFF_WD2   + 1048576ull;     // ~143.7 MB

extern "C" void kernel_launch(void* const* d_in, const int* in_sizes, int n_in,
                              void* d_out, int out_size, void* d_ws, size_t ws_size,
                              hipStream_t stream) {
    if (ws_size < WS_NEED) return;  // leaves d_out poisoned -> visible failure

    const float* vec   = (const float*)d_in[0];
    const int*   wf    = (const int*)d_in[1];
    const int*   goals = (const int*)d_in[2];
    const float* we0   = (const float*)d_in[3];
    const float* we1   = (const float*)d_in[4];
    const float* we2   = (const float*)d_in[5];
    const float* fiW   = (const float*)d_in[6];
    const float* fib   = (const float*)d_in[7];
    const float* encW  = (const float*)d_in[8];
    const float* encb  = (const float*)d_in[9];
    const float* gemb  = (const float*)d_in[10];
    const float* Wih   = (const float*)d_in[11];
    const float* Whh   = (const float*)d_in[12];
    const float* bih   = (const float*)d_in[13];
    const float* bhh   = (const float*)d_in[14];
    const float* diW   = (const float*)d_in[15];
    const float* dib   = (const float*)d_in[16];
    const float* doW   = (const float*)d_in[17];
    const float* dob   = (const float*)d_in[18];

    char* ws = (char*)d_ws;
    ushort_t* G_     = (ushort_t*)(ws + OFF_G);
    ushort_t* Arel   = (ushort_t*)(ws + OFF_AREL);
    ushort_t* WihB   = (ushort_t*)(ws + OFF_WIH);
    ushort_t* WhhF   = (ushort_t*)(ws + OFF_WHHF);
    ushort_t* Hx     = (ushort_t*)(ws + OFF_HX);
    int*      flags  = (int*)(ws + OFF_FLAGS);
    float*    goalD  = (float*)(ws + OFF_GOAL);
    ushort_t* featsA = (ushort_t*)(ws + OFF_FEATS);
    ushort_t* W0     = (ushort_t*)(ws + OFF_W0);
    ushort_t* W1     = (ushort_t*)(ws + OFF_W12);
    ushort_t* W2     = W1 + 262144;
    ushort_t* R0     = (ushort_t*)(ws + OFF_R0);
    ushort_t* R1     = (ushort_t*)(ws + OFF_R1);
    ushort_t* R2     = (ushort_t*)(ws + OFF_R2);
    ushort_t* DecA   = (ushort_t*)(ws + OFF_DECA);
    ushort_t* Wd1    = (ushort_t*)(ws + OFF_WD1);
    ushort_t* D1     = (ushort_t*)(ws + OFF_D1);
    ushort_t* Wd2    = (ushort_t*)(ws + OFF_WD2);

    // zero flags only (kernel-boundary flush makes these visible to atomics).
    // Hx needs NO init: t=0 skips the h-read (h0 == 0).
    hipMemsetAsync(ws + OFF_FLAGS, 0, 1024, stream);

    auto cgrid = [](int n) { int b = (n / 4 + 255) / 256; return b > 2048 ? 2048 : b; };
    k_conv<false><<<cgrid(786432),  256, 0, stream>>>(Wih,  WihB, 786432);
    k_conv<false><<<cgrid(262144),  256, 0, stream>>>(fiW,  W0,   262144);
    k_conv<false><<<cgrid(524288),  256, 0, stream>>>(encW, W1,   524288);
    k_conv<false><<<cgrid(524288),  256, 0, stream>>>(diW,  Wd1,  524288);
    k_conv<false><<<cgrid(524288),  256, 0, stream>>>(doW,  Wd2,  524288);
    k_conv<true ><<<2048,           256, 0, stream>>>(gemb, Arel, 16384000);
    k_whh_frag<<<3072, 256, 0, stream>>>(Whh, WhhF);
    k_feats<<<1024, 256, 0, stream>>>(vec, wf, we0, we1, we2, featsA);

    // G[v] = relu(emb[v]) @ Wih^T + bih   (32000x1536)
    k_gemm<false, true><<<dim3(12, 250), 256, 0, stream>>>(Arel, WihB, bih, G_, 32000, 1536, 512);

    // features branch: 3 GEMMs with relu epilogue
    k_gemm<true, true><<<dim3(4, 4), 256, 0, stream>>>(featsA, W0, fib,        R0, 512, 512, 512);
    k_gemm<true, true><<<dim3(4, 4), 256, 0, stream>>>(R0,     W1, encb,       R1, 512, 512, 512);
    k_gemm<true, true><<<dim3(4, 4), 256, 0, stream>>>(R1,     W2, encb + 512, R2, 512, 512, 512);

    // GRU recurrence (cooperative: 256 co-resident blocks with flag barriers)
    {
        const ushort_t* Gc = G_; const ushort_t* Wc = WhhF;
        const int* gc = goals; const float* bc = bhh;
        ushort_t* hx = Hx; int* fl = flags; float* go = goalD;
        void* kargs[] = { &Gc, &Wc, &gc, &bc, &hx, &fl, &go };
        hipLaunchCooperativeKernel((const void*)k_recur, dim3(256), dim3(128),
                                   kargs, 0, stream);
    }

    // decoder
    k_concat<<<2048, 256, 0, stream>>>(goalD, R2, DecA);
    k_gemm<true,  true ><<<dim3(4, 4), 256, 0, stream>>>(DecA, Wd1, dib, D1, 512, 512, 1024);
    k_gemm<false, false><<<dim3(8, 4), 256, 0, stream>>>(D1, Wd2, dob, (float*)d_out, 512, 1024, 512);
    k_lsm<<<512, 256, 0, stream>>>((float*)d_out);
}

// Round 11
// 1002.337 us; speedup vs baseline: 3.8055x; 1.1699x over previous
//
#include <hip/hip_runtime.h>
#include <hip/hip_bf16.h>

typedef unsigned short ushort_t;
typedef __attribute__((ext_vector_type(8))) short short8;
typedef __attribute__((ext_vector_type(4))) float f32x4;
typedef __attribute__((ext_vector_type(4))) int i32x4;

__device__ __forceinline__ ushort_t f2bf(float f) {
    unsigned x = __builtin_bit_cast(unsigned, f);
    unsigned r = x + 0x7fffu + ((x >> 16) & 1u);
    return (ushort_t)(r >> 16);
}
__device__ __forceinline__ float bf2f(ushort_t u) {
    return __builtin_bit_cast(float, ((unsigned)u) << 16);
}

// coherent-by-construction accesses: bypass L1+L2, hit memory-side L3 (cross-XCD coherent)
__device__ __forceinline__ void store16_cc(void* p, i32x4 v) {
    asm volatile("global_store_dwordx4 %0, %1, off sc0 sc1" :: "v"(p), "v"(v) : "memory");
}
// raw 16B load, NO implicit wait — caller must s_waitcnt before reading result
__device__ __forceinline__ i32x4 load16_cc(const void* p) {
    i32x4 r;
    asm volatile("global_load_dwordx4 %0, %1, off sc0 sc1" : "=v"(r) : "v"(p));
    return r;
}
// raw u16 load, NO implicit wait
__device__ __forceinline__ unsigned load_u16_raw(const ushort_t* p) {
    unsigned r;
    asm volatile("global_load_ushort %0, %1, off" : "=v"(r) : "v"(p));
    return r;
}

// ---------------- generic fp32 -> bf16 convert (optional relu) ----------------
template<bool RELU>
__global__ void k_conv(const float* __restrict__ src, ushort_t* __restrict__ dst, int n) {
    int i = (blockIdx.x * blockDim.x + threadIdx.x) * 4;
    int stride = gridDim.x * blockDim.x * 4;
    for (; i < n; i += stride) {
        float4 v = *(const float4*)(src + i);
        if (RELU) {
            v.x = fmaxf(v.x, 0.f); v.y = fmaxf(v.y, 0.f);
            v.z = fmaxf(v.z, 0.f); v.w = fmaxf(v.w, 0.f);
        }
        dst[i + 0] = f2bf(v.x); dst[i + 1] = f2bf(v.y);
        dst[i + 2] = f2bf(v.z); dst[i + 3] = f2bf(v.w);
    }
}

// ---------------- Whh -> fragment-ordered bf16 [16cg][6f][16kk][64lane][8e] ----
__global__ void k_whh_frag(const float* __restrict__ whh, ushort_t* __restrict__ out) {
    int idx = blockIdx.x * blockDim.x + threadIdx.x;
    if (idx >= 16 * 6 * 16 * 64 * 8) return;
    int e  = idx & 7;
    int s  = idx >> 3;
    int l  = s & 63;
    int s2 = s >> 6;
    int kk = s2 & 15;
    int s3 = s2 >> 4;
    int f  = s3 % 6;
    int j  = s3 / 6;
    int ng = (f >> 1) * 512 + j * 32 + (f & 1) * 16 + (l & 15);
    int k  = kk * 32 + ((l >> 4) << 3) + e;
    out[idx] = f2bf(whh[(size_t)ng * 512 + k]);
}

// ---------------- build feats bf16 [512][512] = [vec | e0 | e1 | e2] ----------
__global__ void k_feats(const float* __restrict__ vec, const int* __restrict__ wf,
                        const float* __restrict__ w0, const float* __restrict__ w1,
                        const float* __restrict__ w2, ushort_t* __restrict__ out) {
    int idx = blockIdx.x * blockDim.x + threadIdx.x;
    if (idx >= 512 * 512) return;
    int b = idx >> 9, k = idx & 511;
    float v;
    if (k < 128)       v = vec[b * 128 + k];
    else if (k < 256)  v = w0[wf[b * 3 + 0] * 128 + (k - 128)];
    else if (k < 384)  v = w1[wf[b * 3 + 1] * 128 + (k - 256)];
    else               v = w2[wf[b * 3 + 2] * 128 + (k - 384)];
    out[idx] = f2bf(v);
}

// ---------------- TN MFMA GEMM: C[M,N] = A[M,K](bf16) @ W[N,K]^T + bias -------
template<bool RELU, bool OUTBF>
__global__ __launch_bounds__(256) void k_gemm(const ushort_t* __restrict__ A,
                                              const ushort_t* __restrict__ W,
                                              const float* __restrict__ bias,
                                              void* __restrict__ Cout,
                                              int M, int N, int K) {
    __shared__ __attribute__((aligned(16))) ushort_t As[128 * 64];
    __shared__ __attribute__((aligned(16))) ushort_t Ws[128 * 64];
    const int tid = threadIdx.x;
    const int lane = tid & 63, w = tid >> 6;
    const int wm = w >> 1, wn = w & 1;
    const int m0 = blockIdx.y * 128, n0 = blockIdx.x * 128;
    const int l16 = lane & 15, lq = lane >> 4;
    f32x4 acc[4][4] = {};

    for (int k0 = 0; k0 < K; k0 += 64) {
        #pragma unroll
        for (int c = 0; c < 4; ++c) {
            int chunk = w * 4 + c;
            int d = chunk * 1024 + lane * 16;
            int row = d >> 7;
            int dlin = d ^ ((row & 7) << 4);
            int col = (dlin & 127) >> 1;
            const ushort_t* ga = A + (size_t)(m0 + row) * K + k0 + col;
            __builtin_amdgcn_global_load_lds(
                (const __attribute__((address_space(1))) void*)ga,
                (__attribute__((address_space(3))) void*)(((char*)As) + chunk * 1024),
                16, 0, 0);
        }
        #pragma unroll
        for (int c = 0; c < 4; ++c) {
            int chunk = w * 4 + c;
            int d = chunk * 1024 + lane * 16;
            int row = d >> 7;
            int dlin = d ^ ((row & 7) << 4);
            int col = (dlin & 127) >> 1;
            const ushort_t* gw = W + (size_t)(n0 + row) * K + k0 + col;
            __builtin_amdgcn_global_load_lds(
                (const __attribute__((address_space(1))) void*)gw,
                (__attribute__((address_space(3))) void*)(((char*)Ws) + chunk * 1024),
                16, 0, 0);
        }
        asm volatile("s_waitcnt vmcnt(0)" ::: "memory");
        __syncthreads();

        #pragma unroll
        for (int kk = 0; kk < 2; ++kk) {
            short8 af[4], bfr[4];
            #pragma unroll
            for (int m = 0; m < 4; ++m) {
                int row = wm * 64 + m * 16 + l16;
                int addr = (row * 128 + kk * 64 + lq * 16) ^ ((row & 7) << 4);
                af[m] = *(const short8*)((const char*)As + addr);
            }
            #pragma unroll
            for (int n = 0; n < 4; ++n) {
                int row = wn * 64 + n * 16 + l16;
                int addr = (row * 128 + kk * 64 + lq * 16) ^ ((row & 7) << 4);
                bfr[n] = *(const short8*)((const char*)Ws + addr);
            }
            #pragma unroll
            for (int m = 0; m < 4; ++m)
                #pragma unroll
                for (int n = 0; n < 4; ++n)
                    acc[m][n] = __builtin_amdgcn_mfma_f32_16x16x32_bf16(af[m], bfr[n], acc[m][n], 0, 0, 0);
        }
        __syncthreads();
    }

    #pragma unroll
    for (int m = 0; m < 4; ++m) {
        int row = m0 + wm * 64 + m * 16 + lq * 4;
        #pragma unroll
        for (int n = 0; n < 4; ++n) {
            int col = n0 + wn * 64 + n * 16 + l16;
            float bv = bias[col];
            #pragma unroll
            for (int r = 0; r < 4; ++r) {
                float v = acc[m][n][r] + bv;
                if (RELU) v = fmaxf(v, 0.f);
                if (OUTBF) ((ushort_t*)Cout)[(size_t)(row + r) * N + col] = f2bf(v);
                else       ((float*)Cout)[(size_t)(row + r) * N + col] = v;
            }
        }
    }
}

// ---------------- GRU recurrence: persistent cooperative, 256 blocks ---------
// block b: rg=b&15 (32 batch rows), cg=b>>4 (32 hid cols). Whh slice in LDS.
// DATAFLOW exchange (no hard barrier): per step, own h-tile comes from LDS (Hs,
// zero wait); peer tiles are consumed in static order via batched flag poll
// (one vector load = all 16 producer states) + 2-deep pipelined sc0/sc1 loads
// with counted s_waitcnt vmcnt(1). G gate-values issued at END of previous
// step (hide under flag release); ONE __syncthreads per step (pre-flag join).
// Back-pressure: a block's step-t+1 poll needs ALL row-peer flags >= t+1, so no
// producer can overwrite buffer t&1 while a peer still reads it.
__global__ __launch_bounds__(128) void k_recur(const ushort_t* __restrict__ G,
                                               const ushort_t* __restrict__ WhhF,
                                               const int* __restrict__ goals,
                                               const float* __restrict__ bhh,
                                               ushort_t* __restrict__ Hx,
                                               int* __restrict__ flags,
                                               float* __restrict__ goal_out) {
    __shared__ __attribute__((aligned(16))) ushort_t Bs[6 * 16 * 64 * 8]; // 98304 B
    __shared__ __attribute__((aligned(16))) ushort_t Hs[32 * 32];         // 2 KB
    __shared__ __attribute__((aligned(16))) int Tk[32 * 128];             // 16 KB tokens
    const int bid = blockIdx.x;
    const int rg = bid & 15;
    const int cg = bid >> 4;
    const int r0 = rg * 32, c0 = cg * 32;
    const int tid = threadIdx.x, lane = tid & 63, w = tid >> 6;
    const int l16 = lane & 15, lq = lane >> 4;

    // stage Whh fragment slice (96 KB) + token slab (16 KB)
    {
        const ushort_t* src = WhhF + (size_t)cg * 49152;
        for (int c = 0; c < 48; ++c) {
            int chunk = w * 48 + c;
            __builtin_amdgcn_global_load_lds(
                (const __attribute__((address_space(1))) void*)(src + chunk * 512 + lane * 8),
                (__attribute__((address_space(3))) void*)(((char*)Bs) + chunk * 1024),
                16, 0, 0);
        }
        const int* tsrc = goals + r0 * 128;
        for (int c = 0; c < 8; ++c) {
            int chunk = w * 8 + c;
            __builtin_amdgcn_global_load_lds(
                (const __attribute__((address_space(1))) void*)(tsrc + chunk * 256 + lane * 4),
                (__attribute__((address_space(3))) void*)(((char*)Tk) + chunk * 1024),
                16, 0, 0);
        }
        asm volatile("s_waitcnt vmcnt(0)" ::: "memory");
        __syncthreads();
    }

    const int rowbase = r0 + w * 16;
    const int lrow = w * 16 + lq * 4;
    float hst[2][4];
    #pragma unroll
    for (int q = 0; q < 2; ++q)
        #pragma unroll
        for (int r = 0; r < 4; ++r) hst[q][r] = 0.f;

    float bh[3][2];
    #pragma unroll
    for (int g = 0; g < 3; ++g)
        #pragma unroll
        for (int q = 0; q < 2; ++q) bh[g][q] = bhh[g * 512 + c0 + q * 16 + l16];

    unsigned gv[3][4][2];
    auto issueGV = [&](int tn) {
        #pragma unroll
        for (int r = 0; r < 4; ++r) {
            int tok = Tk[(lrow + r) * 128 + tn];
            const ushort_t* gr = G + (size_t)tok * 1536;
            #pragma unroll
            for (int q = 0; q < 2; ++q) {
                int cl = c0 + q * 16 + l16;
                gv[0][r][q] = load_u16_raw(gr + cl);
                gv[1][r][q] = load_u16_raw(gr + 512 + cl);
                gv[2][r][q] = load_u16_raw(gr + 1024 + cl);
            }
        }
    };
    issueGV(0);   // prologue: G for t=0 (drained by first vmcnt(0) in-loop)

    int* fp = flags + (((lane & 15) << 4) | rg);

    f32x4 acc[6];
    for (int t = 0; t < 128; ++t) {
        #pragma unroll
        for (int f = 0; f < 6; ++f) acc[f] = (f32x4){0.f, 0.f, 0.f, 0.f};

        auto domfma = [&](short8 af, int kk) {
            #pragma unroll
            for (int f = 0; f < 6; ++f) {
                short8 bfr = *(const short8*)((const char*)Bs + ((f * 16 + kk) * 64 + lane) * 16);
                acc[f] = __builtin_amdgcn_mfma_f32_16x16x32_bf16(af, bfr, acc[f], 0, 0, 0);
            }
        };
        auto pollrdy = [&]() -> unsigned {
            int v;
            asm volatile("global_load_dword %0, %1, off sc0 sc1" : "=v"(v) : "v"(fp));
            asm volatile("s_waitcnt vmcnt(0)" ::: "memory");
            __builtin_amdgcn_sched_barrier(0);
            return (unsigned)(__ballot(v >= t) & 0xffffull);
        };

        if (t) {
            const ushort_t* hb = Hx + ((size_t)(t & 1) << 18);
            auto tadr = [&](int j) {
                return hb + (size_t)(rowbase + l16) * 512 + j * 32 + lq * 8;
            };
            // own tile from LDS — no wait, no flag
            short8 own = *(const short8*)&Hs[(w * 16 + l16) * 32 + lq * 8];
            domfma(own, cg);
            // batched flag poll (also drains the G loads issued last step)
            unsigned rdy = pollrdy();
            // prime the 2-deep pipeline with tile cg+1
            short8 afr[2];
            {
                int j1 = (cg + 1) & 15;
                int guard = 0;
                while (!((rdy >> j1) & 1)) {
                    rdy = pollrdy();
                    if (++guard > 200000) break;
                }
                afr[1] = __builtin_bit_cast(short8, load16_cc(tadr(j1)));
            }
            #pragma unroll
            for (int s = 1; s <= 15; ++s) {
                if (s < 15) {
                    int jn = (cg + s + 1) & 15;
                    int guard = 0;
                    while (!((rdy >> jn) & 1)) {
                        rdy = pollrdy();              // vmcnt(0): drains in-flight tile too (harmless)
                        if (++guard > 200000) break;
                    }
                    afr[(s + 1) & 1] = __builtin_bit_cast(short8, load16_cc(tadr(jn)));
                    asm volatile("s_waitcnt vmcnt(1)" ::: "memory");  // wait the OLDER in-flight tile
                } else {
                    asm volatile("s_waitcnt vmcnt(0)" ::: "memory");
                }
                __builtin_amdgcn_sched_barrier(0);
                domfma(afr[s & 1], (cg + s) & 15);
            }
        } else {
            asm volatile("s_waitcnt vmcnt(0)" ::: "memory");  // drain prologue G
            __builtin_amdgcn_sched_barrier(0);
        }

        // gates + state update (gv drained by the vmcnt(0)s above)
        #pragma unroll
        for (int r = 0; r < 4; ++r) {
            #pragma unroll
            for (int q = 0; q < 2; ++q) {
                float ir = bf2f((ushort_t)gv[0][r][q]);
                float iz = bf2f((ushort_t)gv[1][r][q]);
                float in_ = bf2f((ushort_t)gv[2][r][q]);
                float hr = acc[q][r] + bh[0][q];
                float hz = acc[2 + q][r] + bh[1][q];
                float hn = acc[4 + q][r] + bh[2][q];
                float rr = 1.f / (1.f + __expf(-(ir + hr)));
                float zz = 1.f / (1.f + __expf(-(iz + hz)));
                float x = in_ + rr * hn;
                float ax = fabsf(x);
                float th = 1.f - 2.f / (__expf(2.f * ax) + 1.f);
                th = copysignf(th, x);
                float hnew = (1.f - zz) * th + zz * hst[q][r];
                hst[q][r] = hnew;
                // wave-local Hs rows: wave w owns rows w*16..w*16+15
                Hs[(w * 16 + lq * 4 + r) * 32 + q * 16 + l16] = f2bf(hnew);
            }
        }

        // store own 32x32 tile (wave-local rows: tid>>2 stays within own wave's half)
        {
            int row = tid >> 2, coff = (tid & 3) * 8;
            i32x4 v = *(const i32x4*)&Hs[row * 32 + coff];
            ushort_t* ho = Hx + ((size_t)((t + 1) & 1) << 18)
                         + (size_t)(r0 + row) * 512 + c0 + coff;
            store16_cc(ho, v);
        }
        asm volatile("s_waitcnt vmcnt(0)" ::: "memory");
        __builtin_amdgcn_sched_barrier(0);
        __syncthreads();   // cross-wave join: both waves' stores drained

        if (tid == 0) {
            int fvv = t + 1;
            asm volatile("global_store_dword %0, %1, off sc0 sc1"
                         :: "v"(&flags[bid]), "v"(fvv) : "memory");
        }
        // issue G for next step — latency hides under flag release + next own-MFMA
        issueGV(t < 127 ? t + 1 : 127);
    }

    #pragma unroll
    for (int r = 0; r < 4; ++r) {
        int brow = rowbase + lq * 4 + r;
        #pragma unroll
        for (int q = 0; q < 2; ++q) {
            int cl = c0 + q * 16 + l16;
            goal_out[(size_t)brow * 512 + cl] = hst[q][r];
        }
    }
}

// ---------------- concat: DecA = [bf16(relu(goal)) | R2] ----------------------
__global__ void k_concat(const float* __restrict__ gd, const ushort_t* __restrict__ r2,
                         ushort_t* __restrict__ out) {
    int idx = blockIdx.x * blockDim.x + threadIdx.x;
    if (idx >= 512 * 1024) return;
    int b = idx >> 10, c = idx & 1023;
    out[idx] = (c < 512) ? f2bf(fmaxf(gd[b * 512 + c], 0.f)) : r2[b * 512 + (c - 512)];
}

// ---------------- log_softmax in place, one block per row --------------------
__global__ __launch_bounds__(256) void k_lsm(float* __restrict__ logits) {
    __shared__ float sm[4];
    __shared__ float ss[4];
    float* p = logits + (size_t)blockIdx.x * 1024;
    int tid = threadIdx.x;
    float4 v = ((const float4*)p)[tid];
    float m = fmaxf(fmaxf(v.x, v.y), fmaxf(v.z, v.w));
    #pragma unroll
    for (int o = 32; o >= 1; o >>= 1) m = fmaxf(m, __shfl_xor(m, o));
    if ((tid & 63) == 0) sm[tid >> 6] = m;
    __syncthreads();
    m = fmaxf(fmaxf(sm[0], sm[1]), fmaxf(sm[2], sm[3]));
    float s = __expf(v.x - m) + __expf(v.y - m) + __expf(v.z - m) + __expf(v.w - m);
    #pragma unroll
    for (int o = 32; o >= 1; o >>= 1) s += __shfl_xor(s, o);
    if ((tid & 63) == 0) ss[tid >> 6] = s;
    __syncthreads();
    s = ss[0] + ss[1] + ss[2] + ss[3];
    float lse = m + logf(s);
    v.x -= lse; v.y -= lse; v.z -= lse; v.w -= lse;
    ((float4*)p)[tid] = v;
}

// ---------------- workspace layout -------------------------------------------
static constexpr size_t OFF_G     = 0;                          // 32000x1536 bf16
static constexpr size_t OFF_AREL  = OFF_G     + 98304000ull;    // 32000x512 bf16
static constexpr size_t OFF_WIH   = OFF_AREL  + 32768000ull;    // 1536x512 bf16
static constexpr size_t OFF_WHHF  = OFF_WIH   + 1572864ull;     // frag-ordered
static constexpr size_t OFF_HX    = OFF_WHHF  + 1572864ull;     // 2x512x512 bf16
static constexpr size_t OFF_FLAGS = OFF_HX    + 1048576ull;     // 256 ints
static constexpr size_t OFF_GOAL  = OFF_FLAGS + 1024ull;        // 512x512 f32
static constexpr size_t OFF_FEATS = OFF_GOAL  + 1048576ull;     // 512x512 bf16
static constexpr size_t OFF_W0    = OFF_FEATS + 524288ull;      // 512x512 bf16
static constexpr size_t OFF_W12   = OFF_W0    + 524288ull;      // 2x512x512 bf16
static constexpr size_t OFF_R0    = OFF_W12   + 1048576ull;
static constexpr size_t OFF_R1    = OFF_R0    + 524288ull;
static constexpr size_t OFF_R2    = OFF_R1    + 524288ull;
static constexpr size_t OFF_DECA  = OFF_R2    + 524288ull;      // 512x1024 bf16
static constexpr size_t OFF_WD1   = OFF_DECA  + 1048576ull;     // 512x1024 bf16
static constexpr size_t OFF_D1    = OFF_WD1   + 1048576ull;     // 512x512 bf16
static constexpr size_t OFF_WD2   = OFF_D1    + 524288ull;      // 1024x512 bf16
static constexpr size_t WS_NEED   = OFF_WD2   + 1048576ull;     // ~143.7 MB

extern "C" void kernel_launch(void* const* d_in, const int* in_sizes, int n_in,
                              void* d_out, int out_size, void* d_ws, size_t ws_size,
                              hipStream_t stream) {
    if (ws_size < WS_NEED) return;  // leaves d_out poisoned -> visible failure

    const float* vec   = (const float*)d_in[0];
    const int*   wf    = (const int*)d_in[1];
    const int*   goals = (const int*)d_in[2];
    const float* we0   = (const float*)d_in[3];
    const float* we1   = (const float*)d_in[4];
    const float* we2   = (const float*)d_in[5];
    const float* fiW   = (const float*)d_in[6];
    const float* fib   = (const float*)d_in[7];
    const float* encW  = (const float*)d_in[8];
    const float* encb  = (const float*)d_in[9];
    const float* gemb  = (const float*)d_in[10];
    const float* Wih   = (const float*)d_in[11];
    const float* Whh   = (const float*)d_in[12];
    const float* bih   = (const float*)d_in[13];
    const float* bhh   = (const float*)d_in[14];
    const float* diW   = (const float*)d_in[15];
    const float* dib   = (const float*)d_in[16];
    const float* doW   = (const float*)d_in[17];
    const float* dob   = (const float*)d_in[18];

    char* ws = (char*)d_ws;
    ushort_t* G_     = (ushort_t*)(ws + OFF_G);
    ushort_t* Arel   = (ushort_t*)(ws + OFF_AREL);
    ushort_t* WihB   = (ushort_t*)(ws + OFF_WIH);
    ushort_t* WhhF   = (ushort_t*)(ws + OFF_WHHF);
    ushort_t* Hx     = (ushort_t*)(ws + OFF_HX);
    int*      flags  = (int*)(ws + OFF_FLAGS);
    float*    goalD  = (float*)(ws + OFF_GOAL);
    ushort_t* featsA = (ushort_t*)(ws + OFF_FEATS);
    ushort_t* W0     = (ushort_t*)(ws + OFF_W0);
    ushort_t* W1     = (ushort_t*)(ws + OFF_W12);
    ushort_t* W2     = W1 + 262144;
    ushort_t* R0     = (ushort_t*)(ws + OFF_R0);
    ushort_t* R1     = (ushort_t*)(ws + OFF_R1);
    ushort_t* R2     = (ushort_t*)(ws + OFF_R2);
    ushort_t* DecA   = (ushort_t*)(ws + OFF_DECA);
    ushort_t* Wd1    = (ushort_t*)(ws + OFF_WD1);
    ushort_t* D1     = (ushort_t*)(ws + OFF_D1);
    ushort_t* Wd2    = (ushort_t*)(ws + OFF_WD2);

    // zero flags only. Hx needs NO init: t=0 skips tile reads (h0 == 0).
    hipMemsetAsync(ws + OFF_FLAGS, 0, 1024, stream);

    auto cgrid = [](int n) { int b = (n / 4 + 255) / 256; return b > 2048 ? 2048 : b; };
    k_conv<false><<<cgrid(786432),  256, 0, stream>>>(Wih,  WihB, 786432);
    k_conv<false><<<cgrid(262144),  256, 0, stream>>>(fiW,  W0,   262144);
    k_conv<false><<<cgrid(524288),  256, 0, stream>>>(encW, W1,   524288);
    k_conv<false><<<cgrid(524288),  256, 0, stream>>>(diW,  Wd1,  524288);
    k_conv<false><<<cgrid(524288),  256, 0, stream>>>(doW,  Wd2,  524288);
    k_conv<true ><<<2048,           256, 0, stream>>>(gemb, Arel, 16384000);
    k_whh_frag<<<3072, 256, 0, stream>>>(Whh, WhhF);
    k_feats<<<1024, 256, 0, stream>>>(vec, wf, we0, we1, we2, featsA);

    // G[v] = relu(emb[v]) @ Wih^T + bih   (32000x1536)
    k_gemm<false, true><<<dim3(12, 250), 256, 0, stream>>>(Arel, WihB, bih, G_, 32000, 1536, 512);

    // features branch: 3 GEMMs with relu epilogue
    k_gemm<true, true><<<dim3(4, 4), 256, 0, stream>>>(featsA, W0, fib,        R0, 512, 512, 512);
    k_gemm<true, true><<<dim3(4, 4), 256, 0, stream>>>(R0,     W1, encb,       R1, 512, 512, 512);
    k_gemm<true, true><<<dim3(4, 4), 256, 0, stream>>>(R1,     W2, encb + 512, R2, 512, 512, 512);

    // GRU recurrence (cooperative: 256 co-resident blocks, dataflow exchange)
    {
        const ushort_t* Gc = G_; const ushort_t* Wc = WhhF;
        const int* gc = goals; const float* bc = bhh;
        ushort_t* hx = Hx; int* fl = flags; float* go = goalD;
        void* kargs[] = { &Gc, &Wc, &gc, &bc, &hx, &fl, &go };
        hipLaunchCooperativeKernel((const void*)k_recur, dim3(256), dim3(128),
                                   kargs, 0, stream);
    }

    // decoder
    k_concat<<<2048, 256, 0, stream>>>(goalD, R2, DecA);
    k_gemm<true,  true ><<<dim3(4, 4), 256, 0, stream>>>(DecA, Wd1, dib, D1, 512, 512, 1024);
    k_gemm<false, false><<<dim3(8, 4), 256, 0, stream>>>(D1, Wd2, dob, (float*)d_out, 512, 1024, 512);
    k_lsm<<<512, 256, 0, stream>>>((float*)d_out);
}